// Round 4
// baseline (444.726 us; speedup 1.0000x reference)
//
#include <hip/hip_runtime.h>
#include <hip/hip_bf16.h>

using bf16 = __hip_bfloat16;

typedef float floatx4 __attribute__((ext_vector_type(4)));
typedef short shortx8 __attribute__((ext_vector_type(8)));
typedef __bf16 bf16x8 __attribute__((ext_vector_type(8)));

#define NEG_BIG -3.0e38f

// async global->LDS DMA, 16 B per lane; LDS dest = wave-uniform base + lane*16
#define GLOAD_LDS16(g, l)                                                     \
  __builtin_amdgcn_global_load_lds(                                           \
      (const __attribute__((address_space(1))) unsigned int*)(g),             \
      (__attribute__((address_space(3))) unsigned int*)(l), 16, 0, 0)

__device__ __forceinline__ float bf2f(short s) {
  union { unsigned int u; float f; } x;
  x.u = ((unsigned int)(unsigned short)s) << 16;
  return x.f;
}

// ---------------- dtype sniff: cos[0]==1.0 exactly.
// fp32 -> word0 = 0x3F800000 ; bf16 -> word0 = 0x3F803F80 (two packed 1.0's)
__global__ void sniff_k(const void* __restrict__ cosp, int* __restrict__ flag) {
  unsigned w = *(const unsigned*)cosp;
  *flag = (w == 0x3F800000u) ? 1 : 0;  // 1 = inputs are fp32
}

// ---------------- generic input -> bf16 convert, vectorized x8 ----------------
__global__ void conv_k(const void* __restrict__ src, bf16* __restrict__ dst, int n8,
                       const int* __restrict__ flag) {
  int i = blockIdx.x * blockDim.x + threadIdx.x;
  if (i >= n8) return;
  shortx8 r;
  if (*flag) {
    const float4* s4 = (const float4*)src;
    float4 x0 = s4[i * 2], x1 = s4[i * 2 + 1];
    float xs[8] = {x0.x, x0.y, x0.z, x0.w, x1.x, x1.y, x1.z, x1.w};
#pragma unroll
    for (int e = 0; e < 8; ++e)
      r[e] = (short)__bfloat16_as_ushort(__float2bfloat16(xs[e]));
  } else {
    r = ((const shortx8*)src)[i];
  }
  *(shortx8*)(dst + (size_t)i * 8) = r;
}

// ---------------- fused convert + transpose: src (2048, C) -> dst (C, 2048) bf16 ------
__global__ void transpose_conv_k(const void* __restrict__ src, bf16* __restrict__ dst,
                                 int C, const int* __restrict__ flag) {
  __shared__ bf16 tile[32][33];
  int fp32 = *flag;
  int tx = threadIdx.x, ty = threadIdx.y;
  int c0 = blockIdx.x * 32, r0 = blockIdx.y * 32;
#pragma unroll
  for (int i = 0; i < 32; i += 8) {
    size_t idx = (size_t)(r0 + ty + i) * C + c0 + tx;
    tile[ty + i][tx] = fp32 ? __float2bfloat16(((const float*)src)[idx])
                            : ((const bf16*)src)[idx];
  }
  __syncthreads();
#pragma unroll
  for (int i = 0; i < 32; i += 8)
    dst[(size_t)(c0 + ty + i) * 2048 + r0 + tx] = tile[tx][ty + i];
}

// ---------------- GEMM: C(M,N) = A(M,K) @ Bt(N,K)^T, bf16 in, fp32 acc ----------------
// m97-style staging: global_load_lds width=16 into UNPADDED [128][32] LDS tiles.
#define BM 128
#define BN 128
#define BK 32

__global__ __launch_bounds__(256) void gemm_bt(const bf16* __restrict__ A,
                                               const bf16* __restrict__ Bt,
                                               void* __restrict__ Cp,
                                               int M, int N, int K,
                                               const int* __restrict__ flag,
                                               int f32out_en) {
  __shared__ __align__(16) short sA[BM][BK];
  __shared__ __align__(16) short sB[BN][BK];
  const int f32out = f32out_en ? *flag : 0;
  const int tid = threadIdx.x;
  const int wave = tid >> 6, lane = tid & 63;
  const int wr = wave >> 1, wc = wave & 1;
  const int lrow = lane & 15, quad = lane >> 4;
  const int m0 = blockIdx.y * BM, n0 = blockIdx.x * BN;

  floatx4 acc[4][4];
#pragma unroll
  for (int r = 0; r < 4; ++r)
#pragma unroll
    for (int c = 0; c < 4; ++c)
      acc[r][c] = (floatx4){0.f, 0.f, 0.f, 0.f};

  const int l4r = lane >> 2;        // 0..15: row within wave chunk
  const int l4c = (lane & 3) * 8;   // col segment (8 bf16 = 16 B)
  const bf16* gA0 = A  + (size_t)(m0 + wave * 16 + l4r) * K + l4c;
  const bf16* gA1 = gA0 + (size_t)64 * K;
  const bf16* gB0 = Bt + (size_t)(n0 + wave * 16 + l4r) * K + l4c;
  const bf16* gB1 = gB0 + (size_t)64 * K;
  short* ldsA0 = &sA[wave * 16][0];
  short* ldsA1 = &sA[64 + wave * 16][0];
  short* ldsB0 = &sB[wave * 16][0];
  short* ldsB1 = &sB[64 + wave * 16][0];

  for (int kk = 0; kk < K; kk += BK) {
    GLOAD_LDS16(gA0 + kk, ldsA0);
    GLOAD_LDS16(gA1 + kk, ldsA1);
    GLOAD_LDS16(gB0 + kk, ldsB0);
    GLOAD_LDS16(gB1 + kk, ldsB1);
    __syncthreads();  // drains vmcnt (DMA complete) + barrier

    bf16x8 af[4], bfr[4];
#pragma unroll
    for (int r = 0; r < 4; ++r)
      af[r] = __builtin_bit_cast(bf16x8, *(const shortx8*)&sA[wr * 64 + r * 16 + lrow][quad * 8]);
#pragma unroll
    for (int c = 0; c < 4; ++c)
      bfr[c] = __builtin_bit_cast(bf16x8, *(const shortx8*)&sB[wc * 64 + c * 16 + lrow][quad * 8]);
#pragma unroll
    for (int r = 0; r < 4; ++r)
#pragma unroll
      for (int c = 0; c < 4; ++c)
        acc[r][c] = __builtin_amdgcn_mfma_f32_16x16x32_bf16(af[r], bfr[c], acc[r][c], 0, 0, 0);
    __syncthreads();
  }

#pragma unroll
  for (int r = 0; r < 4; ++r) {
#pragma unroll
    for (int c = 0; c < 4; ++c) {
      int mrow = m0 + wr * 64 + r * 16 + quad * 4;
      int ncol = n0 + wc * 64 + c * 16 + lrow;
      if (f32out) {
#pragma unroll
        for (int i = 0; i < 4; ++i)
          ((float*)Cp)[(size_t)(mrow + i) * N + ncol] = acc[r][c][i];
      } else {
#pragma unroll
        for (int i = 0; i < 4; ++i)
          ((bf16*)Cp)[(size_t)(mrow + i) * N + ncol] = __float2bfloat16(acc[r][c][i]);
      }
    }
  }
}

// ---------------- RoPE in-place on q (heads 0..31) and k (kv heads 0..7) ----------------
__global__ void rope_k(bf16* __restrict__ qkv, const bf16* __restrict__ cosb,
                       const bf16* __restrict__ sinb) {
  int idx = blockIdx.x * blockDim.x + threadIdx.x;  // 4096*40*4 = 655360
  int i8 = (idx & 3) * 8;
  int head = (idx >> 2) % 40;
  int m = idx / 160;
  if (m >= 4096) return;
  int p = m & 2047;
  size_t base = (size_t)m * 3072 + (head < 32 ? head * 64 : 2048 + (head - 32) * 64);
  shortx8 a8 = *(const shortx8*)(qkv + base + i8);
  shortx8 b8 = *(const shortx8*)(qkv + base + 32 + i8);
  const bf16* cp = cosb + p * 64 + i8;
  const bf16* sp = sinb + p * 64 + i8;
  shortx8 c0 = *(const shortx8*)cp;
  shortx8 s0 = *(const shortx8*)sp;
  shortx8 c1 = *(const shortx8*)(cp + 32);
  shortx8 s1 = *(const shortx8*)(sp + 32);
  shortx8 ra, rb;
#pragma unroll
  for (int e = 0; e < 8; ++e) {
    float a = bf2f(a8[e]), bb = bf2f(b8[e]);
    ra[e] = (short)__bfloat16_as_ushort(__float2bfloat16(a * bf2f(c0[e]) - bb * bf2f(s0[e])));
    rb[e] = (short)__bfloat16_as_ushort(__float2bfloat16(bb * bf2f(c1[e]) + a * bf2f(s1[e])));
  }
  *(shortx8*)(qkv + base + i8) = ra;
  *(shortx8*)(qkv + base + 32 + i8) = rb;
}

// ---------------- V pre-transpose: qkv V region -> Vt[b][kvh][d][kv], rotation fused ---
// Vt[(b*8+kvh)*64 + d][jt*64 + c] = V[b][kv = jt*64 + ((c - (d&56)) & 63)][kvh][d].
// Per-64-tile rotation (kv + (d&56)) & 63 is the attn sVt bank-stagger, pre-applied so
// attn stages V with linear ds_write_b128 (m173 pre-swizzle pattern).
__global__ void vt_k(const bf16* __restrict__ qkv, bf16* __restrict__ Vt) {
  __shared__ __align__(16) short tile[64][72];
  const int jt = blockIdx.x, kvh = blockIdx.y, b = blockIdx.z;
  const int t = threadIdx.x;
  const int r = t >> 2, seg = (t & 3) * 16;
  const bf16* src = qkv + (size_t)(b * 2048 + jt * 64 + r) * 3072 + 2560 + kvh * 64 + seg;
  *(int4*)&tile[r][seg]     = *(const int4*)src;
  *(int4*)&tile[r][seg + 8] = *(const int4*)(src + 8);
  __syncthreads();
  bf16* dst = Vt + ((size_t)(b * 8 + kvh) * 64 + r) * 2048 + jt * 64 + seg;
  short out[16];
#pragma unroll
  for (int e = 0; e < 16; ++e)
    out[e] = tile[(seg + e - (r & 56)) & 63][r];
  *(int4*)dst       = *(int4*)&out[0];
  *(int4*)(dst + 8) = *(int4*)&out[8];
}

// ---------------- flash attention (causal, GQA 4:1) — MFMA, 128-row Q-tile ----------
// KVBLK=128: per-TILE overheads (max-reduce shuffles, O-rescale, barriers, loop) are
// halved per kv element vs KVBLK=64; per-ELEMENT work (MFMA, exp, sP traffic) is
// unchanged. PV runs in two 64-kv halves through one sP buffer (same-wave WAR through
// LDS is ordered, no barrier needed) to stay under the 64 KB static LDS limit:
// sK 18.4K + sVt 17.4K + sP 18.4K = 54.3 KB; 2 blocks/CU = 108.5 KB (grid-bound).
// T13 defer-rescale: skip alpha/rescale pass unless __any(pmax > m+8); P bounded by
// e^8, f32 accum absorbs it, softmax normalization unaffected.
// R2 lesson: work per block must be uniform — phase pair qt=p then 15-p gives every
// block exactly (p+1)+(16-p) = 17 128-kv iters. R1 lesson: no min-waves hint (spill).
__global__ __launch_bounds__(256) void attn_k(const bf16* __restrict__ qkv,
                                              const bf16* __restrict__ Vt,
                                              bf16* __restrict__ O) {
  const int S = 2048, LDQ = 3072, D = 2048;
  const int p = blockIdx.x, h = blockIdx.y, b = blockIdx.z;
  const int kvh = h >> 2;
  const int tid = threadIdx.x;
  const int w = tid >> 6, lane = tid & 63;
  const int quad = lane >> 4, l15 = lane & 15;

  __shared__ __align__(16) short sK [128][72];   // [kv pos][hd]
  __shared__ __align__(16) short sVt[64][136];   // [hd][2x rotated 64-kv]
  __shared__ __align__(16) short sP [4][32][72]; // per-wave P half-tile round-trip

  // K staging: 128 rows x 64 d; thread = (row = tid>>1, 32-d half = tid&1)
  const int krow = tid >> 1, kseg = (tid & 1) * 32;
  const bf16* kbase = qkv + (size_t)(b * S) * LDQ + 2048 + kvh * 64 + kseg;
  // V staging: 64 d rows x 128 kv; thread = (d = tid>>2, 32-kv seg = tid&3)
  const int vrow = tid >> 2, vseg = (tid & 3) * 32;
  const bf16* vbase = Vt + ((size_t)(b * 8 + kvh) * 64 + vrow) * 2048 + vseg;

  for (int phase = 0; phase < 2; ++phase) {
    const int qt = phase ? (15 - p) : p;
    const int q0 = qt * 128;

    // Q fragments: 2 sub-tiles x 2 k-halves, pre-scaled by 1/sqrt(64)
    bf16x8 qa[2][2];
#pragma unroll
    for (int mt = 0; mt < 2; ++mt) {
      const bf16* qp = qkv + (size_t)(b * S + q0 + w * 32 + mt * 16 + l15) * LDQ + h * 64 + quad * 8;
      qa[mt][0] = __builtin_bit_cast(bf16x8, *(const shortx8*)qp);
      qa[mt][1] = __builtin_bit_cast(bf16x8, *(const shortx8*)(qp + 32));
    }
#pragma unroll
    for (int mt = 0; mt < 2; ++mt)
#pragma unroll
      for (int kk = 0; kk < 2; ++kk)
#pragma unroll
        for (int e = 0; e < 8; ++e)
          qa[mt][kk][e] = (__bf16)((float)qa[mt][kk][e] * 0.125f);

    floatx4 oacc[2][4];
    float m_i[2][4], l_p[2][4];
#pragma unroll
    for (int mt = 0; mt < 2; ++mt) {
#pragma unroll
      for (int d = 0; d < 4; ++d) oacc[mt][d] = (floatx4){0.f, 0.f, 0.f, 0.f};
#pragma unroll
      for (int i = 0; i < 4; ++i) { m_i[mt][i] = NEG_BIG; l_p[mt][i] = 0.f; }
    }

    const int jtEnd = qt + 1;  // 128-kv tiles
    // prefetch tile 0
    {
      const bf16* kp = kbase + (size_t)krow * LDQ;
      const bf16* vp = vbase;
      int4 kr0 = *(const int4*)kp,        kr1 = *(const int4*)(kp + 8);
      int4 kr2 = *(const int4*)(kp + 16), kr3 = *(const int4*)(kp + 24);
      int4 vr0 = *(const int4*)vp,        vr1 = *(const int4*)(vp + 8);
      int4 vr2 = *(const int4*)(vp + 16), vr3 = *(const int4*)(vp + 24);

      for (int jt = 0; jt < jtEnd; ++jt) {
        // ---- stage prefetched K and V (linear vector writes) ----
        *(int4*)&sK[krow][kseg]       = kr0;
        *(int4*)&sK[krow][kseg + 8]   = kr1;
        *(int4*)&sK[krow][kseg + 16]  = kr2;
        *(int4*)&sK[krow][kseg + 24]  = kr3;
        *(int4*)&sVt[vrow][vseg]      = vr0;
        *(int4*)&sVt[vrow][vseg + 8]  = vr1;
        *(int4*)&sVt[vrow][vseg + 16] = vr2;
        *(int4*)&sVt[vrow][vseg + 24] = vr3;
        if (jt + 1 < jtEnd) {
          const bf16* kp2 = kbase + (size_t)((jt + 1) * 128 + krow) * LDQ;
          kr0 = *(const int4*)kp2;        kr1 = *(const int4*)(kp2 + 8);
          kr2 = *(const int4*)(kp2 + 16); kr3 = *(const int4*)(kp2 + 24);
          const bf16* vp2 = vbase + (jt + 1) * 128;
          vr0 = *(const int4*)vp2;        vr1 = *(const int4*)(vp2 + 8);
          vr2 = *(const int4*)(vp2 + 16); vr3 = *(const int4*)(vp2 + 24);
        }
        __syncthreads();

        // ---- S = Q K^T: 32x128 per wave; K B-frags shared by both mt ----
        floatx4 sfr[2][8];
#pragma unroll
        for (int mt = 0; mt < 2; ++mt)
#pragma unroll
          for (int nb = 0; nb < 8; ++nb) sfr[mt][nb] = (floatx4){0.f, 0.f, 0.f, 0.f};
#pragma unroll
        for (int kk = 0; kk < 2; ++kk) {
#pragma unroll
          for (int nb = 0; nb < 8; ++nb) {
            bf16x8 bfr = __builtin_bit_cast(bf16x8,
                *(const shortx8*)&sK[nb * 16 + l15][kk * 32 + quad * 8]);
            sfr[0][nb] = __builtin_amdgcn_mfma_f32_16x16x32_bf16(qa[0][kk], bfr, sfr[0][nb], 0, 0, 0);
            sfr[1][nb] = __builtin_amdgcn_mfma_f32_16x16x32_bf16(qa[1][kk], bfr, sfr[1][nb], 0, 0, 0);
          }
        }

        // ---- mask (last tile only), row max, deferred rescale ----
        float pmax[2][4];
#pragma unroll
        for (int mt = 0; mt < 2; ++mt) {
          if (jt == qt) {
#pragma unroll
            for (int nb = 0; nb < 8; ++nb) {
              int jg = jt * 128 + nb * 16 + l15;
#pragma unroll
              for (int i = 0; i < 4; ++i) {
                int rg = q0 + w * 32 + mt * 16 + quad * 4 + i;
                if (jg > rg) sfr[mt][nb][i] = NEG_BIG;
              }
            }
          }
#pragma unroll
          for (int i = 0; i < 4; ++i) {
            float a = fmaxf(sfr[mt][0][i], sfr[mt][1][i]);
            float bm = fmaxf(sfr[mt][2][i], sfr[mt][3][i]);
            float c = fmaxf(sfr[mt][4][i], sfr[mt][5][i]);
            float d = fmaxf(sfr[mt][6][i], sfr[mt][7][i]);
            float m = fmaxf(fmaxf(a, bm), fmaxf(c, d));
            m = fmaxf(m, __shfl_xor(m, 1));
            m = fmaxf(m, __shfl_xor(m, 2));
            m = fmaxf(m, __shfl_xor(m, 4));
            m = fmaxf(m, __shfl_xor(m, 8));
            pmax[mt][i] = m;
          }
        }
#pragma unroll
        for (int mt = 0; mt < 2; ++mt) {
          bool grow = (pmax[mt][0] > m_i[mt][0] + 8.f) ||
                      (pmax[mt][1] > m_i[mt][1] + 8.f) ||
                      (pmax[mt][2] > m_i[mt][2] + 8.f) ||
                      (pmax[mt][3] > m_i[mt][3] + 8.f);
          if (__any((int)grow)) {
#pragma unroll
            for (int i = 0; i < 4; ++i) {
              float Mn = fmaxf(m_i[mt][i], pmax[mt][i]);
              float alpha = __expf(m_i[mt][i] - Mn);
              m_i[mt][i] = Mn;
              l_p[mt][i] *= alpha;
#pragma unroll
              for (int d = 0; d < 4; ++d) oacc[mt][d][i] *= alpha;
            }
          }
        }

        // ---- P = exp(S - m) and O += P V, in two 64-kv halves through sP ----
        float rs[2][4] = {{0.f, 0.f, 0.f, 0.f}, {0.f, 0.f, 0.f, 0.f}};
#pragma unroll
        for (int hf = 0; hf < 2; ++hf) {
#pragma unroll
          for (int mt = 0; mt < 2; ++mt) {
#pragma unroll
            for (int nb2 = 0; nb2 < 4; ++nb2) {
#pragma unroll
              for (int i = 0; i < 4; ++i) {
                float pv = __expf(sfr[mt][hf * 4 + nb2][i] - m_i[mt][i]);
                rs[mt][i] += pv;
                sP[w][mt * 16 + quad * 4 + i][nb2 * 16 + l15] =
                    (short)__bfloat16_as_ushort(__float2bfloat16(pv));
              }
            }
          }
#pragma unroll
          for (int kk = 0; kk < 2; ++kk) {
            bf16x8 af0 = __builtin_bit_cast(bf16x8,
                *(const shortx8*)&sP[w][l15][kk * 32 + quad * 8]);
            bf16x8 af1 = __builtin_bit_cast(bf16x8,
                *(const shortx8*)&sP[w][16 + l15][kk * 32 + quad * 8]);
#pragma unroll
            for (int db = 0; db < 4; ++db) {
              int row = db * 16 + l15;
              int col = hf * 64 + ((kk * 32 + quad * 8 + (row & 56)) & 63);
              bf16x8 bfr = __builtin_bit_cast(bf16x8, *(const shortx8*)&sVt[row][col]);
              oacc[0][db] = __builtin_amdgcn_mfma_f32_16x16x32_bf16(af0, bfr, oacc[0][db], 0, 0, 0);
              oacc[1][db] = __builtin_amdgcn_mfma_f32_16x16x32_bf16(af1, bfr, oacc[1][db], 0, 0, 0);
            }
          }
        }
#pragma unroll
        for (int mt = 0; mt < 2; ++mt)
#pragma unroll
          for (int i = 0; i < 4; ++i) l_p[mt][i] += rs[mt][i];
        __syncthreads();  // before next tile overwrites sK/sVt
      }
    }

    // ---- epilogue: reduce lane-partial l across the quad, store O rows ----
#pragma unroll
    for (int mt = 0; mt < 2; ++mt) {
#pragma unroll
      for (int i = 0; i < 4; ++i) {
        float l = l_p[mt][i];
        l += __shfl_xor(l, 1);
        l += __shfl_xor(l, 2);
        l += __shfl_xor(l, 4);
        l += __shfl_xor(l, 8);
        float inv = 1.f / l;
        bf16* op = O + (size_t)(b * S + q0 + w * 32 + mt * 16 + quad * 4 + i) * D + h * 64 + l15;
#pragma unroll
        for (int d = 0; d < 4; ++d)
          op[d * 16] = __float2bfloat16(oacc[mt][d][i] * inv);
      }
    }
  }
}

// ---------------- launch ----------------
// ws layout (bf16 elements from ws16 = d_ws + 16; flag int at d_ws):
//   xb 8.4M | cosb/sinb 131k | bt_qkv 6.3M | wot 4.2M | qkv 12.6M  (~63.4 MB)
// Vt (2M elems = 4 MB) reuses bt_qkv, which is dead after the QKV GEMM.
extern "C" void kernel_launch(void* const* d_in, const int* in_sizes, int n_in,
                              void* d_out, int out_size, void* d_ws, size_t ws_size,
                              hipStream_t stream) {
  const void* x    = d_in[0];
  const void* cosp = d_in[1];
  const void* sinp = d_in[2];
  const void* wq   = d_in[3];
  const void* wk   = d_in[4];
  const void* wv   = d_in[5];
  const void* wo   = d_in[6];

  int* flag = (int*)d_ws;
  bf16* ws16 = (bf16*)((char*)d_ws + 16);
  bf16* xb     = ws16;
  bf16* cosb   = xb + (size_t)8388608;
  bf16* sinb   = cosb + 131072;
  bf16* bt_qkv = sinb + 131072;
  bf16* wot    = bt_qkv + (size_t)3072 * 2048;
  bf16* qkv    = wot + (size_t)2048 * 2048;
  bf16* o      = xb;      // x dead after QKV GEMM; attn output reuses it
  bf16* vt     = bt_qkv;  // weights dead after QKV GEMM; Vt reuses the slot

  sniff_k<<<1, 1, 0, stream>>>(cosp, flag);

  conv_k<<<(1048576 + 255) / 256, 256, 0, stream>>>(x, xb, 1048576, flag);
  conv_k<<<(16384 + 255) / 256, 256, 0, stream>>>(cosp, cosb, 16384, flag);
  conv_k<<<(16384 + 255) / 256, 256, 0, stream>>>(sinp, sinb, 16384, flag);

  dim3 tb(32, 8);
  transpose_conv_k<<<dim3(64, 64), tb, 0, stream>>>(wq, bt_qkv, 2048, flag);
  transpose_conv_k<<<dim3(16, 64), tb, 0, stream>>>(wk, bt_qkv + (size_t)2048 * 2048, 512, flag);
  transpose_conv_k<<<dim3(16, 64), tb, 0, stream>>>(wv, bt_qkv + (size_t)2560 * 2048, 512, flag);
  transpose_conv_k<<<dim3(64, 64), tb, 0, stream>>>(wo, wot, 2048, flag);

  // QKV projection: (4096,2048) @ (2048,3072), bf16 out
  gemm_bt<<<dim3(3072 / BN, 4096 / BM), 256, 0, stream>>>(xb, bt_qkv, qkv,
                                                          4096, 3072, 2048, flag, 0);

  rope_k<<<2560, 256, 0, stream>>>(qkv, cosb, sinb);

  // V pre-transpose (+bank rotation) into the dead weight slot
  vt_k<<<dim3(32, 8, 2), 256, 0, stream>>>(qkv, vt);

  // attention: 512 uniform blocks (phase pair in-block), 8x32x2 grid
  attn_k<<<dim3(8, 32, 2), 256, 0, stream>>>(qkv, vt, o);

  // output projection: (4096,2048) @ (2048,2048); output dtype follows input dtype
  gemm_bt<<<dim3(2048 / BN, 4096 / BM), 256, 0, stream>>>(o, wot, d_out,
                                                          4096, 2048, 2048, flag, 1);
}

// Round 5
// 387.655 us; speedup vs baseline: 1.1472x; 1.1472x over previous
//
#include <hip/hip_runtime.h>
#include <hip/hip_bf16.h>

using bf16 = __hip_bfloat16;

typedef float floatx4 __attribute__((ext_vector_type(4)));
typedef short shortx8 __attribute__((ext_vector_type(8)));
typedef short shortx4 __attribute__((ext_vector_type(4)));
typedef __bf16 bf16x8 __attribute__((ext_vector_type(8)));

#define NEG_BIG -3.0e38f

// async global->LDS DMA, 16 B per lane; LDS dest = wave-uniform base + lane*16
#define GLOAD_LDS16(g, l)                                                     \
  __builtin_amdgcn_global_load_lds(                                           \
      (const __attribute__((address_space(1))) unsigned int*)(g),             \
      (__attribute__((address_space(3))) unsigned int*)(l), 16, 0, 0)

__device__ __forceinline__ float bf2f(short s) {
  union { unsigned int u; float f; } x;
  x.u = ((unsigned int)(unsigned short)s) << 16;
  return x.f;
}

// ---------------- dtype sniff: cos[0]==1.0 exactly.
// fp32 -> word0 = 0x3F800000 ; bf16 -> word0 = 0x3F803F80 (two packed 1.0's)
__global__ void sniff_k(const void* __restrict__ cosp, int* __restrict__ flag) {
  unsigned w = *(const unsigned*)cosp;
  *flag = (w == 0x3F800000u) ? 1 : 0;  // 1 = inputs are fp32
}

// ---------------- generic input -> bf16 convert, vectorized x8 ----------------
__global__ void conv_k(const void* __restrict__ src, bf16* __restrict__ dst, int n8,
                       const int* __restrict__ flag) {
  int i = blockIdx.x * blockDim.x + threadIdx.x;
  if (i >= n8) return;
  shortx8 r;
  if (*flag) {
    const float4* s4 = (const float4*)src;
    float4 x0 = s4[i * 2], x1 = s4[i * 2 + 1];
    float xs[8] = {x0.x, x0.y, x0.z, x0.w, x1.x, x1.y, x1.z, x1.w};
#pragma unroll
    for (int e = 0; e < 8; ++e)
      r[e] = (short)__bfloat16_as_ushort(__float2bfloat16(xs[e]));
  } else {
    r = ((const shortx8*)src)[i];
  }
  *(shortx8*)(dst + (size_t)i * 8) = r;
}

// ---------------- fused convert + transpose: src (2048, C) -> dst (C, 2048) bf16 ------
__global__ void transpose_conv_k(const void* __restrict__ src, bf16* __restrict__ dst,
                                 int C, const int* __restrict__ flag) {
  __shared__ bf16 tile[32][33];
  int fp32 = *flag;
  int tx = threadIdx.x, ty = threadIdx.y;
  int c0 = blockIdx.x * 32, r0 = blockIdx.y * 32;
#pragma unroll
  for (int i = 0; i < 32; i += 8) {
    size_t idx = (size_t)(r0 + ty + i) * C + c0 + tx;
    tile[ty + i][tx] = fp32 ? __float2bfloat16(((const float*)src)[idx])
                            : ((const bf16*)src)[idx];
  }
  __syncthreads();
#pragma unroll
  for (int i = 0; i < 32; i += 8)
    dst[(size_t)(c0 + ty + i) * 2048 + r0 + tx] = tile[tx][ty + i];
}

// ---------------- GEMM: C(M,N) = A(M,K) @ Bt(N,K)^T, bf16 in, fp32 acc ----------------
// m97-style staging: global_load_lds width=16 into UNPADDED [128][32] LDS tiles.
#define BM 128
#define BN 128
#define BK 32

__global__ __launch_bounds__(256) void gemm_bt(const bf16* __restrict__ A,
                                               const bf16* __restrict__ Bt,
                                               void* __restrict__ Cp,
                                               int M, int N, int K,
                                               const int* __restrict__ flag,
                                               int f32out_en) {
  __shared__ __align__(16) short sA[BM][BK];
  __shared__ __align__(16) short sB[BN][BK];
  const int f32out = f32out_en ? *flag : 0;
  const int tid = threadIdx.x;
  const int wave = tid >> 6, lane = tid & 63;
  const int wr = wave >> 1, wc = wave & 1;
  const int lrow = lane & 15, quad = lane >> 4;
  const int m0 = blockIdx.y * BM, n0 = blockIdx.x * BN;

  floatx4 acc[4][4];
#pragma unroll
  for (int r = 0; r < 4; ++r)
#pragma unroll
    for (int c = 0; c < 4; ++c)
      acc[r][c] = (floatx4){0.f, 0.f, 0.f, 0.f};

  const int l4r = lane >> 2;        // 0..15: row within wave chunk
  const int l4c = (lane & 3) * 8;   // col segment (8 bf16 = 16 B)
  const bf16* gA0 = A  + (size_t)(m0 + wave * 16 + l4r) * K + l4c;
  const bf16* gA1 = gA0 + (size_t)64 * K;
  const bf16* gB0 = Bt + (size_t)(n0 + wave * 16 + l4r) * K + l4c;
  const bf16* gB1 = gB0 + (size_t)64 * K;
  short* ldsA0 = &sA[wave * 16][0];
  short* ldsA1 = &sA[64 + wave * 16][0];
  short* ldsB0 = &sB[wave * 16][0];
  short* ldsB1 = &sB[64 + wave * 16][0];

  for (int kk = 0; kk < K; kk += BK) {
    GLOAD_LDS16(gA0 + kk, ldsA0);
    GLOAD_LDS16(gA1 + kk, ldsA1);
    GLOAD_LDS16(gB0 + kk, ldsB0);
    GLOAD_LDS16(gB1 + kk, ldsB1);
    __syncthreads();  // drains vmcnt (DMA complete) + barrier

    bf16x8 af[4], bfr[4];
#pragma unroll
    for (int r = 0; r < 4; ++r)
      af[r] = __builtin_bit_cast(bf16x8, *(const shortx8*)&sA[wr * 64 + r * 16 + lrow][quad * 8]);
#pragma unroll
    for (int c = 0; c < 4; ++c)
      bfr[c] = __builtin_bit_cast(bf16x8, *(const shortx8*)&sB[wc * 64 + c * 16 + lrow][quad * 8]);
#pragma unroll
    for (int r = 0; r < 4; ++r)
#pragma unroll
      for (int c = 0; c < 4; ++c)
        acc[r][c] = __builtin_amdgcn_mfma_f32_16x16x32_bf16(af[r], bfr[c], acc[r][c], 0, 0, 0);
    __syncthreads();
  }

#pragma unroll
  for (int r = 0; r < 4; ++r) {
#pragma unroll
    for (int c = 0; c < 4; ++c) {
      int mrow = m0 + wr * 64 + r * 16 + quad * 4;
      int ncol = n0 + wc * 64 + c * 16 + lrow;
      if (f32out) {
#pragma unroll
        for (int i = 0; i < 4; ++i)
          ((float*)Cp)[(size_t)(mrow + i) * N + ncol] = acc[r][c][i];
      } else {
#pragma unroll
        for (int i = 0; i < 4; ++i)
          ((bf16*)Cp)[(size_t)(mrow + i) * N + ncol] = __float2bfloat16(acc[r][c][i]);
      }
    }
  }
}

// ---------------- RoPE in-place on q (heads 0..31) and k (kv heads 0..7) ----------------
__global__ void rope_k(bf16* __restrict__ qkv, const bf16* __restrict__ cosb,
                       const bf16* __restrict__ sinb) {
  int idx = blockIdx.x * blockDim.x + threadIdx.x;  // 4096*40*4 = 655360
  int i8 = (idx & 3) * 8;
  int head = (idx >> 2) % 40;
  int m = idx / 160;
  if (m >= 4096) return;
  int p = m & 2047;
  size_t base = (size_t)m * 3072 + (head < 32 ? head * 64 : 2048 + (head - 32) * 64);
  shortx8 a8 = *(const shortx8*)(qkv + base + i8);
  shortx8 b8 = *(const shortx8*)(qkv + base + 32 + i8);
  const bf16* cp = cosb + p * 64 + i8;
  const bf16* sp = sinb + p * 64 + i8;
  shortx8 c0 = *(const shortx8*)cp;
  shortx8 s0 = *(const shortx8*)sp;
  shortx8 c1 = *(const shortx8*)(cp + 32);
  shortx8 s1 = *(const shortx8*)(sp + 32);
  shortx8 ra, rb;
#pragma unroll
  for (int e = 0; e < 8; ++e) {
    float a = bf2f(a8[e]), bb = bf2f(b8[e]);
    ra[e] = (short)__bfloat16_as_ushort(__float2bfloat16(a * bf2f(c0[e]) - bb * bf2f(s0[e])));
    rb[e] = (short)__bfloat16_as_ushort(__float2bfloat16(bb * bf2f(c1[e]) + a * bf2f(s1[e])));
  }
  *(shortx8*)(qkv + base + i8) = ra;
  *(shortx8*)(qkv + base + 32 + i8) = rb;
}

// ---------------- V pre-transpose: qkv V region -> Vt[b][kvh][d][kv] (plain) ----------
// No bank rotation: the swapped-PV read pattern (b64 at col = 32kk+16g+quad*4, row =
// db*16+l15, row stride 36 dwords) lands 2 lanes/bank = conflict-free as-is.
__global__ void vt_k(const bf16* __restrict__ qkv, bf16* __restrict__ Vt) {
  __shared__ __align__(16) short tile[64][72];
  const int jt = blockIdx.x, kvh = blockIdx.y, b = blockIdx.z;
  const int t = threadIdx.x;
  const int r = t >> 2, seg = (t & 3) * 16;
  const bf16* src = qkv + (size_t)(b * 2048 + jt * 64 + r) * 3072 + 2560 + kvh * 64 + seg;
  *(int4*)&tile[r][seg]     = *(const int4*)src;
  *(int4*)&tile[r][seg + 8] = *(const int4*)(src + 8);
  __syncthreads();
  bf16* dst = Vt + ((size_t)(b * 8 + kvh) * 64 + r) * 2048 + jt * 64 + seg;
  short out[16];
#pragma unroll
  for (int e = 0; e < 16; ++e)
    out[e] = tile[seg + e][r];
  *(int4*)dst       = *(int4*)&out[0];
  *(int4*)(dst + 8) = *(int4*)&out[8];
}

// ---------------- flash attention (causal, GQA 4:1) — swapped-QK^T, in-reg softmax ---
// R4 lesson: KVBLK=128 blew VGPR to 168 (occupancy 20->11%, +26 us) — stay at 64.
// Structural change vs R3: compute mfma(K,Q) instead of mfma(Q,K). A/B fragment lane
// layouts are identical to the old reads (zero staging change), but the score output
// becomes S[kv=quad*4+i][q=l15]: each lane owns ONE q-row per mt, so
//   - row max = 15 in-lane fmax + shfl_xor(16,32)   (was 16 shuffles per mt)
//   - m_i, l_p are one scalar per mt                (was [mt][4])
//   - P is consumed by PV directly from registers: the kv-order inside a K=32 MFMA is
//     free, so pick sigma(quad*8+e) = 32kk+16(e>>2)+4quad+(e&3) = exactly the kvs this
//     lane already holds; V's B-frag reads the same sigma via two ds_read_b64.
//   => the sP LDS round-trip (32 ds_write_b16 + 4 ds_read_b128/iter) is DELETED.
// alpha/l for O-rows (q=quad*4+i) come from lane (lane&48)|(quad*4+i) via __shfl —
// only on T13 rescale events (threshold 8) and in the epilogue.
// Freed LDS -> double-buffered K/V, ONE barrier per kv-iter (was 2).
// R2 lesson: uniform work per block (phase pair qt=p, 15-p). R1 lesson: no min-waves hint.
__global__ __launch_bounds__(256) void attn_k(const bf16* __restrict__ qkv,
                                              const bf16* __restrict__ Vt,
                                              bf16* __restrict__ O) {
  const int S = 2048, LDQ = 3072, D = 2048;
  const int p = blockIdx.x, h = blockIdx.y, b = blockIdx.z;
  const int kvh = h >> 2;
  const int tid = threadIdx.x;
  const int w = tid >> 6, lane = tid & 63;
  const int quad = lane >> 4, l15 = lane & 15;

  __shared__ __align__(16) short sK [2][64][72];  // [buf][kv pos][hd]
  __shared__ __align__(16) short sVt[2][64][72];  // [buf][hd][kv pos]

  const int srow = tid >> 2, sseg = (tid & 3) * 16;
  const bf16* kbase = qkv + (size_t)(b * S) * LDQ + 2048 + kvh * 64 + sseg;       // row=kv
  const bf16* vbase = Vt + ((size_t)(b * 8 + kvh) * 64 + srow) * 2048 + sseg;     // row=d

  for (int phase = 0; phase < 2; ++phase) {
    const int qt = phase ? (15 - p) : p;
    const int q0 = qt * 128;

    // Q fragments: 2 sub-tiles x 2 k-halves, pre-scaled by 1/sqrt(64) (exact in bf16)
    bf16x8 qa[2][2];
#pragma unroll
    for (int mt = 0; mt < 2; ++mt) {
      const bf16* qp = qkv + (size_t)(b * S + q0 + w * 32 + mt * 16 + l15) * LDQ + h * 64 + quad * 8;
      qa[mt][0] = __builtin_bit_cast(bf16x8, *(const shortx8*)qp);
      qa[mt][1] = __builtin_bit_cast(bf16x8, *(const shortx8*)(qp + 32));
    }
#pragma unroll
    for (int mt = 0; mt < 2; ++mt)
#pragma unroll
      for (int kk = 0; kk < 2; ++kk)
#pragma unroll
        for (int e = 0; e < 8; ++e)
          qa[mt][kk][e] = (__bf16)((float)qa[mt][kk][e] * 0.125f);

    floatx4 oacc[2][4];
    float m_i[2], l_p[2];
#pragma unroll
    for (int mt = 0; mt < 2; ++mt) {
#pragma unroll
      for (int d = 0; d < 4; ++d) oacc[mt][d] = (floatx4){0.f, 0.f, 0.f, 0.f};
      m_i[mt] = NEG_BIG; l_p[mt] = 0.f;
    }

    const int jtEnd = 2 * qt + 2;

    // stage tile 0 into buf 0
    {
      const bf16* kp = kbase + (size_t)srow * LDQ;
      *(int4*)&sK [0][srow][sseg]     = *(const int4*)kp;
      *(int4*)&sK [0][srow][sseg + 8] = *(const int4*)(kp + 8);
      *(int4*)&sVt[0][srow][sseg]     = *(const int4*)vbase;
      *(int4*)&sVt[0][srow][sseg + 8] = *(const int4*)(vbase + 8);
    }
    __syncthreads();

    int cur = 0;
    for (int jt = 0; jt < jtEnd; ++jt) {
      // ---- prefetch next tile into regs (global; latency hides under compute) ----
      int4 kr0, kr1, vr0, vr1;
      const bool pre = (jt + 1 < jtEnd);
      if (pre) {
        const bf16* kp2 = kbase + (size_t)((jt + 1) * 64 + srow) * LDQ;
        kr0 = *(const int4*)kp2;
        kr1 = *(const int4*)(kp2 + 8);
        const bf16* vp2 = vbase + (jt + 1) * 64;
        vr0 = *(const int4*)vp2;
        vr1 = *(const int4*)(vp2 + 8);
      }

      // ---- S^T = K Q^T: lane holds S[kv=nb*16+quad*4+i][q=l15] in sfr[mt][nb][i] ----
      floatx4 sfr[2][4];
#pragma unroll
      for (int mt = 0; mt < 2; ++mt)
#pragma unroll
        for (int nb = 0; nb < 4; ++nb) sfr[mt][nb] = (floatx4){0.f, 0.f, 0.f, 0.f};
#pragma unroll
      for (int kk = 0; kk < 2; ++kk) {
#pragma unroll
        for (int nb = 0; nb < 4; ++nb) {
          bf16x8 kf = __builtin_bit_cast(bf16x8,
              *(const shortx8*)&sK[cur][nb * 16 + l15][kk * 32 + quad * 8]);
          sfr[0][nb] = __builtin_amdgcn_mfma_f32_16x16x32_bf16(kf, qa[0][kk], sfr[0][nb], 0, 0, 0);
          sfr[1][nb] = __builtin_amdgcn_mfma_f32_16x16x32_bf16(kf, qa[1][kk], sfr[1][nb], 0, 0, 0);
        }
      }

      // ---- per mt: mask, in-lane row softmax with T13 defer ----
#pragma unroll
      for (int mt = 0; mt < 2; ++mt) {
        if (jt >= 2 * qt) {  // diagonal-crossing tiles only
          const int rg = q0 + w * 32 + mt * 16 + l15;
#pragma unroll
          for (int nb = 0; nb < 4; ++nb)
#pragma unroll
            for (int i = 0; i < 4; ++i) {
              int jg = jt * 64 + nb * 16 + quad * 4 + i;
              if (jg > rg) sfr[mt][nb][i] = NEG_BIG;
            }
        }
        // row max: 16 in-lane values + cross-quad reduce
        float m = fmaxf(fmaxf(sfr[mt][0][0], sfr[mt][0][1]), fmaxf(sfr[mt][0][2], sfr[mt][0][3]));
#pragma unroll
        for (int nb = 1; nb < 4; ++nb)
#pragma unroll
          for (int i = 0; i < 4; ++i) m = fmaxf(m, sfr[mt][nb][i]);
        m = fmaxf(m, __shfl_xor(m, 16));
        m = fmaxf(m, __shfl_xor(m, 32));

        bool grow = m > m_i[mt] + 8.f;
        if (__any((int)grow)) {
          float Mn = fmaxf(m_i[mt], m);
          float alpha = __expf(m_i[mt] - Mn);   // quad-uniform per l15-row
          m_i[mt] = Mn;
          l_p[mt] *= alpha;
#pragma unroll
          for (int i = 0; i < 4; ++i) {
            float ai = __shfl(alpha, (lane & 48) | (quad * 4 + i));
#pragma unroll
            for (int d = 0; d < 4; ++d) oacc[mt][d][i] *= ai;
          }
        }
        // exp in place + row-partial sum (lane-local)
        float rs = 0.f;
#pragma unroll
        for (int nb = 0; nb < 4; ++nb)
#pragma unroll
          for (int i = 0; i < 4; ++i) {
            float pv = __expf(sfr[mt][nb][i] - m_i[mt]);
            sfr[mt][nb][i] = pv;
            rs += pv;
          }
        l_p[mt] += rs;
      }

      // ---- O += P V: P as in-register A-frags (sigma-permuted), V via 2x ds_read_b64 --
#pragma unroll
      for (int kk = 0; kk < 2; ++kk) {
        bf16x8 pf0, pf1;
#pragma unroll
        for (int e = 0; e < 4; ++e) {
          pf0[e]     = (__bf16)sfr[0][2 * kk][e];
          pf0[e + 4] = (__bf16)sfr[0][2 * kk + 1][e];
          pf1[e]     = (__bf16)sfr[1][2 * kk][e];
          pf1[e + 4] = (__bf16)sfr[1][2 * kk + 1][e];
        }
#pragma unroll
        for (int db = 0; db < 4; ++db) {
          const short* vrow = &sVt[cur][db * 16 + l15][0];
          shortx4 va = *(const shortx4*)(vrow + kk * 32 + quad * 4);
          shortx4 vb = *(const shortx4*)(vrow + kk * 32 + 16 + quad * 4);
          bf16x8 vf = __builtin_bit_cast(bf16x8,
              __builtin_shufflevector(va, vb, 0, 1, 2, 3, 4, 5, 6, 7));
          oacc[0][db] = __builtin_amdgcn_mfma_f32_16x16x32_bf16(pf0, vf, oacc[0][db], 0, 0, 0);
          oacc[1][db] = __builtin_amdgcn_mfma_f32_16x16x32_bf16(pf1, vf, oacc[1][db], 0, 0, 0);
        }
      }

      // ---- write prefetched tile into the other buffer; single barrier ----
      if (pre) {
        *(int4*)&sK [cur ^ 1][srow][sseg]     = kr0;
        *(int4*)&sK [cur ^ 1][srow][sseg + 8] = kr1;
        *(int4*)&sVt[cur ^ 1][srow][sseg]     = vr0;
        *(int4*)&sVt[cur ^ 1][srow][sseg + 8] = vr1;
      }
      __syncthreads();
      cur ^= 1;
    }

    // ---- epilogue: cross-quad l reduce, alpha-style shfl for O-rows, store ----
#pragma unroll
    for (int mt = 0; mt < 2; ++mt) {
      float l = l_p[mt];
      l += __shfl_xor(l, 16);
      l += __shfl_xor(l, 32);
      float inv = 1.f / l;
#pragma unroll
      for (int i = 0; i < 4; ++i) {
        float ii = __shfl(inv, (lane & 48) | (quad * 4 + i));
        bf16* op = O + (size_t)(b * S + q0 + w * 32 + mt * 16 + quad * 4 + i) * D + h * 64 + l15;
#pragma unroll
        for (int db = 0; db < 4; ++db)
          op[db * 16] = __float2bfloat16(oacc[mt][db][i] * ii);
      }
    }
  }
}

// ---------------- launch ----------------
// ws layout (bf16 elements from ws16 = d_ws + 16; flag int at d_ws):
//   xb 8.4M | cosb/sinb 131k | bt_qkv 6.3M | wot 4.2M | qkv 12.6M  (~63.4 MB)
// Vt (2M elems = 4 MB) reuses bt_qkv, which is dead after the QKV GEMM.
extern "C" void kernel_launch(void* const* d_in, const int* in_sizes, int n_in,
                              void* d_out, int out_size, void* d_ws, size_t ws_size,
                              hipStream_t stream) {
  const void* x    = d_in[0];
  const void* cosp = d_in[1];
  const void* sinp = d_in[2];
  const void* wq   = d_in[3];
  const void* wk   = d_in[4];
  const void* wv   = d_in[5];
  const void* wo   = d_in[6];

  int* flag = (int*)d_ws;
  bf16* ws16 = (bf16*)((char*)d_ws + 16);
  bf16* xb     = ws16;
  bf16* cosb   = xb + (size_t)8388608;
  bf16* sinb   = cosb + 131072;
  bf16* bt_qkv = sinb + 131072;
  bf16* wot    = bt_qkv + (size_t)3072 * 2048;
  bf16* qkv    = wot + (size_t)2048 * 2048;
  bf16* o      = xb;      // x dead after QKV GEMM; attn output reuses it
  bf16* vt     = bt_qkv;  // weights dead after QKV GEMM; Vt reuses the slot

  sniff_k<<<1, 1, 0, stream>>>(cosp, flag);

  conv_k<<<(1048576 + 255) / 256, 256, 0, stream>>>(x, xb, 1048576, flag);
  conv_k<<<(16384 + 255) / 256, 256, 0, stream>>>(cosp, cosb, 16384, flag);
  conv_k<<<(16384 + 255) / 256, 256, 0, stream>>>(sinp, sinb, 16384, flag);

  dim3 tb(32, 8);
  transpose_conv_k<<<dim3(64, 64), tb, 0, stream>>>(wq, bt_qkv, 2048, flag);
  transpose_conv_k<<<dim3(16, 64), tb, 0, stream>>>(wk, bt_qkv + (size_t)2048 * 2048, 512, flag);
  transpose_conv_k<<<dim3(16, 64), tb, 0, stream>>>(wv, bt_qkv + (size_t)2560 * 2048, 512, flag);
  transpose_conv_k<<<dim3(64, 64), tb, 0, stream>>>(wo, wot, 2048, flag);

  // QKV projection: (4096,2048) @ (2048,3072), bf16 out
  gemm_bt<<<dim3(3072 / BN, 4096 / BM), 256, 0, stream>>>(xb, bt_qkv, qkv,
                                                          4096, 3072, 2048, flag, 0);

  rope_k<<<2560, 256, 0, stream>>>(qkv, cosb, sinb);

  // V pre-transpose into the dead weight slot
  vt_k<<<dim3(32, 8, 2), 256, 0, stream>>>(qkv, vt);

  // attention: 512 uniform blocks (phase pair in-block), 8x32x2 grid
  attn_k<<<dim3(8, 32, 2), 256, 0, stream>>>(qkv, vt, o);

  // output projection: (4096,2048) @ (2048,2048); output dtype follows input dtype
  gemm_bt<<<dim3(2048 / BN, 4096 / BM), 256, 0, stream>>>(o, wot, d_out,
                                                          4096, 2048, 2048, flag, 1);
}

// Round 6
// 349.680 us; speedup vs baseline: 1.2718x; 1.1086x over previous
//
#include <hip/hip_runtime.h>
#include <hip/hip_bf16.h>

using bf16 = __hip_bfloat16;

typedef float floatx4 __attribute__((ext_vector_type(4)));
typedef short shortx8 __attribute__((ext_vector_type(8)));
typedef short shortx4 __attribute__((ext_vector_type(4)));
typedef __bf16 bf16x8 __attribute__((ext_vector_type(8)));

#define NEG_BIG -3.0e38f

// async global->LDS DMA, 16 B per lane; LDS dest = wave-uniform base + lane*16
#define GLOAD_LDS16(g, l)                                                     \
  __builtin_amdgcn_global_load_lds(                                           \
      (const __attribute__((address_space(1))) unsigned int*)(g),             \
      (__attribute__((address_space(3))) unsigned int*)(l), 16, 0, 0)

__device__ __forceinline__ float bf2f(short s) {
  union { unsigned int u; float f; } x;
  x.u = ((unsigned int)(unsigned short)s) << 16;
  return x.f;
}

// ---------------- dtype sniff: cos[0]==1.0 exactly.
// fp32 -> word0 = 0x3F800000 ; bf16 -> word0 = 0x3F803F80 (two packed 1.0's)
__global__ void sniff_k(const void* __restrict__ cosp, int* __restrict__ flag) {
  unsigned w = *(const unsigned*)cosp;
  *flag = (w == 0x3F800000u) ? 1 : 0;  // 1 = inputs are fp32
}

// ---------------- generic input -> bf16 convert, vectorized x8 ----------------
__global__ void conv_k(const void* __restrict__ src, bf16* __restrict__ dst, int n8,
                       const int* __restrict__ flag) {
  int i = blockIdx.x * blockDim.x + threadIdx.x;
  if (i >= n8) return;
  shortx8 r;
  if (*flag) {
    const float4* s4 = (const float4*)src;
    float4 x0 = s4[i * 2], x1 = s4[i * 2 + 1];
    float xs[8] = {x0.x, x0.y, x0.z, x0.w, x1.x, x1.y, x1.z, x1.w};
#pragma unroll
    for (int e = 0; e < 8; ++e)
      r[e] = (short)__bfloat16_as_ushort(__float2bfloat16(xs[e]));
  } else {
    r = ((const shortx8*)src)[i];
  }
  *(shortx8*)(dst + (size_t)i * 8) = r;
}

// ---------------- fused convert + transpose: src (2048, C) -> dst (C, 2048) bf16 ------
__global__ void transpose_conv_k(const void* __restrict__ src, bf16* __restrict__ dst,
                                 int C, const int* __restrict__ flag) {
  __shared__ bf16 tile[32][33];
  int fp32 = *flag;
  int tx = threadIdx.x, ty = threadIdx.y;
  int c0 = blockIdx.x * 32, r0 = blockIdx.y * 32;
#pragma unroll
  for (int i = 0; i < 32; i += 8) {
    size_t idx = (size_t)(r0 + ty + i) * C + c0 + tx;
    tile[ty + i][tx] = fp32 ? __float2bfloat16(((const float*)src)[idx])
                            : ((const bf16*)src)[idx];
  }
  __syncthreads();
#pragma unroll
  for (int i = 0; i < 32; i += 8)
    dst[(size_t)(c0 + ty + i) * 2048 + r0 + tx] = tile[tx][ty + i];
}

// ---------------- GEMM 256x256: C(M,N) = A(M,K) @ Bt(N,K)^T, bf16 in, fp32 acc -------
// R5 analysis: the 128^2 m97-structure capped at ~456 TF on these shapes (its
// documented ceiling class; source-pipelining tweaks on it are neutral). This kernel
// is the 256^2 deep-pipeline geometry:
//  - 8 waves (512 thr), per-wave output 128x64 (acc[8][4] = 128 VGPR).
//  - 4-deep LDS ring of K=32 tiles (4 x 32 KB = 128 KB), depth-2 prefetch.
//  - ONE raw s_barrier + counted vmcnt(8) per K-tile (T4: never drain in-loop).
//    Safety: stage(t+2) overwrites buf of t-2; the stage is issued after barrier(t-1),
//    which is after ALL waves' compute(t-2). Reads of tile t are covered by vmcnt(8)
//    (own oldest 4 = tile t's loads) + barrier.
//  - T2-lite swizzle: 64B rows have 4 16B slots; col ^= ((row&3)<<4) applied on the
//    per-lane GLOBAL source (linear DMA dest, rule #21) and on ds_read addresses:
//    8-way column-slice conflict -> 4-way.
//  - T1 XCD swizzle (both grids divisible by 8: 192, 128).
#define NKSTEP 32

__global__ __launch_bounds__(512) void gemm256(const bf16* __restrict__ A,
                                               const bf16* __restrict__ Bt,
                                               void* __restrict__ Cp,
                                               int M, int N, int K,
                                               const int* __restrict__ flag,
                                               int f32out_en) {
  __shared__ __align__(16) short lds[4][16384];  // [ring buf][A 8192 | B 8192] shorts
  const int f32out = f32out_en ? *flag : 0;
  const int tid = threadIdx.x;
  const int w = tid >> 6, lane = tid & 63;
  const int wr = w >> 2, wc = w & 3;
  const int quad = lane >> 4, l15 = lane & 15;

  // XCD-aware bijective swizzle (nwg % 8 == 0 for both launches)
  const int nwg = gridDim.x;
  const int id = blockIdx.x;
  const int swz = (id & 7) * (nwg >> 3) + (id >> 3);
  const int nbx = N >> 8;
  const int bx = swz % nbx, by = swz / nbx;
  const int m0 = by << 8, n0 = bx << 8;

  // staging source addresses (inverse-swizzled): lane covers row rl, 16B slot
  // (lane&3)^(rl&3) of a 64B row segment
  const int rl = lane >> 2;
  const int c8 = (((lane & 3) ^ (rl & 3)) << 3);
  const bf16* gA0 = A  + (size_t)(m0 + w * 32 + rl) * K + c8;
  const bf16* gA1 = gA0 + (size_t)16 * K;
  const bf16* gB0 = Bt + (size_t)(n0 + w * 32 + rl) * K + c8;
  const bf16* gB1 = gB0 + (size_t)16 * K;

  floatx4 acc[8][4];
#pragma unroll
  for (int r = 0; r < 8; ++r)
#pragma unroll
    for (int c = 0; c < 4; ++c)
      acc[r][c] = (floatx4){0.f, 0.f, 0.f, 0.f};

  // swizzled ds_read offsets (shorts); row&3 == l15&3 for 16-aligned row bases
  const int xr = (quad * 8) ^ ((l15 & 3) << 3);
  const int aoff = (wr * 128 + l15) * 32 + xr;
  const int boff = 8192 + (wc * 64 + l15) * 32 + xr;

  const int nkt = K >> 5;

#define STAGE256(tt)                                                          \
  do {                                                                        \
    short* d_ = &lds[(tt) & 3][0];                                            \
    const int k0_ = (tt) << 5;                                                \
    GLOAD_LDS16(gA0 + k0_, d_ + (w << 10));                                   \
    GLOAD_LDS16(gA1 + k0_, d_ + (w << 10) + 512);                             \
    GLOAD_LDS16(gB0 + k0_, d_ + 8192 + (w << 10));                            \
    GLOAD_LDS16(gB1 + k0_, d_ + 8192 + (w << 10) + 512);                      \
  } while (0)

  STAGE256(0);
  STAGE256(1);

  for (int t = 0; t < nkt; ++t) {
    if (t + 2 < nkt) {
      STAGE256(t + 2);
      asm volatile("s_waitcnt vmcnt(8)" ::: "memory");   // tile t's 4 done; 8 in flight
    } else if (t + 1 < nkt) {
      asm volatile("s_waitcnt vmcnt(4)" ::: "memory");
    } else {
      asm volatile("s_waitcnt vmcnt(0)" ::: "memory");
    }
    __builtin_amdgcn_s_barrier();
    __builtin_amdgcn_sched_barrier(0);  // keep ds_reads below the barrier

    const short* bufS = &lds[t & 3][0];
    bf16x8 af[8], bfr[4];
#pragma unroll
    for (int r = 0; r < 8; ++r)
      af[r] = __builtin_bit_cast(bf16x8, *(const shortx8*)(bufS + aoff + r * 512));
#pragma unroll
    for (int c = 0; c < 4; ++c)
      bfr[c] = __builtin_bit_cast(bf16x8, *(const shortx8*)(bufS + boff + c * 512));
#pragma unroll
    for (int r = 0; r < 8; ++r)
#pragma unroll
      for (int c = 0; c < 4; ++c)
        acc[r][c] = __builtin_amdgcn_mfma_f32_16x16x32_bf16(af[r], bfr[c], acc[r][c], 0, 0, 0);
  }

#pragma unroll
  for (int r = 0; r < 8; ++r) {
#pragma unroll
    for (int c = 0; c < 4; ++c) {
      int mrow = m0 + wr * 128 + r * 16 + quad * 4;
      int ncol = n0 + wc * 64 + c * 16 + l15;
      if (f32out) {
#pragma unroll
        for (int i = 0; i < 4; ++i)
          ((float*)Cp)[(size_t)(mrow + i) * N + ncol] = acc[r][c][i];
      } else {
#pragma unroll
        for (int i = 0; i < 4; ++i)
          ((bf16*)Cp)[(size_t)(mrow + i) * N + ncol] = __float2bfloat16(acc[r][c][i]);
      }
    }
  }
}

// ---------------- RoPE in-place on q (heads 0..31) and k (kv heads 0..7) ----------------
__global__ void rope_k(bf16* __restrict__ qkv, const bf16* __restrict__ cosb,
                       const bf16* __restrict__ sinb) {
  int idx = blockIdx.x * blockDim.x + threadIdx.x;  // 4096*40*4 = 655360
  int i8 = (idx & 3) * 8;
  int head = (idx >> 2) % 40;
  int m = idx / 160;
  if (m >= 4096) return;
  int p = m & 2047;
  size_t base = (size_t)m * 3072 + (head < 32 ? head * 64 : 2048 + (head - 32) * 64);
  shortx8 a8 = *(const shortx8*)(qkv + base + i8);
  shortx8 b8 = *(const shortx8*)(qkv + base + 32 + i8);
  const bf16* cp = cosb + p * 64 + i8;
  const bf16* sp = sinb + p * 64 + i8;
  shortx8 c0 = *(const shortx8*)cp;
  shortx8 s0 = *(const shortx8*)sp;
  shortx8 c1 = *(const shortx8*)(cp + 32);
  shortx8 s1 = *(const shortx8*)(sp + 32);
  shortx8 ra, rb;
#pragma unroll
  for (int e = 0; e < 8; ++e) {
    float a = bf2f(a8[e]), bb = bf2f(b8[e]);
    ra[e] = (short)__bfloat16_as_ushort(__float2bfloat16(a * bf2f(c0[e]) - bb * bf2f(s0[e])));
    rb[e] = (short)__bfloat16_as_ushort(__float2bfloat16(bb * bf2f(c1[e]) + a * bf2f(s1[e])));
  }
  *(shortx8*)(qkv + base + i8) = ra;
  *(shortx8*)(qkv + base + 32 + i8) = rb;
}

// ---------------- V pre-transpose: qkv V region -> Vt[b][kvh][d][kv] (plain) ----------
__global__ void vt_k(const bf16* __restrict__ qkv, bf16* __restrict__ Vt) {
  __shared__ __align__(16) short tile[64][72];
  const int jt = blockIdx.x, kvh = blockIdx.y, b = blockIdx.z;
  const int t = threadIdx.x;
  const int r = t >> 2, seg = (t & 3) * 16;
  const bf16* src = qkv + (size_t)(b * 2048 + jt * 64 + r) * 3072 + 2560 + kvh * 64 + seg;
  *(int4*)&tile[r][seg]     = *(const int4*)src;
  *(int4*)&tile[r][seg + 8] = *(const int4*)(src + 8);
  __syncthreads();
  bf16* dst = Vt + ((size_t)(b * 8 + kvh) * 64 + r) * 2048 + jt * 64 + seg;
  short out[16];
#pragma unroll
  for (int e = 0; e < 16; ++e)
    out[e] = tile[seg + e][r];
  *(int4*)dst       = *(int4*)&out[0];
  *(int4*)(dst + 8) = *(int4*)&out[8];
}

// ---------------- flash attention (causal, GQA 4:1) — swapped-QK^T, in-reg softmax ---
// (unchanged from R5: ~100-105 us, below both GEMMs)
__global__ __launch_bounds__(256) void attn_k(const bf16* __restrict__ qkv,
                                              const bf16* __restrict__ Vt,
                                              bf16* __restrict__ O) {
  const int S = 2048, LDQ = 3072, D = 2048;
  const int p = blockIdx.x, h = blockIdx.y, b = blockIdx.z;
  const int kvh = h >> 2;
  const int tid = threadIdx.x;
  const int w = tid >> 6, lane = tid & 63;
  const int quad = lane >> 4, l15 = lane & 15;

  __shared__ __align__(16) short sK [2][64][72];  // [buf][kv pos][hd]
  __shared__ __align__(16) short sVt[2][64][72];  // [buf][hd][kv pos]

  const int srow = tid >> 2, sseg = (tid & 3) * 16;
  const bf16* kbase = qkv + (size_t)(b * S) * LDQ + 2048 + kvh * 64 + sseg;       // row=kv
  const bf16* vbase = Vt + ((size_t)(b * 8 + kvh) * 64 + srow) * 2048 + sseg;     // row=d

  for (int phase = 0; phase < 2; ++phase) {
    const int qt = phase ? (15 - p) : p;
    const int q0 = qt * 128;

    // Q fragments: 2 sub-tiles x 2 k-halves, pre-scaled by 1/sqrt(64) (exact in bf16)
    bf16x8 qa[2][2];
#pragma unroll
    for (int mt = 0; mt < 2; ++mt) {
      const bf16* qp = qkv + (size_t)(b * S + q0 + w * 32 + mt * 16 + l15) * LDQ + h * 64 + quad * 8;
      qa[mt][0] = __builtin_bit_cast(bf16x8, *(const shortx8*)qp);
      qa[mt][1] = __builtin_bit_cast(bf16x8, *(const shortx8*)(qp + 32));
    }
#pragma unroll
    for (int mt = 0; mt < 2; ++mt)
#pragma unroll
      for (int kk = 0; kk < 2; ++kk)
#pragma unroll
        for (int e = 0; e < 8; ++e)
          qa[mt][kk][e] = (__bf16)((float)qa[mt][kk][e] * 0.125f);

    floatx4 oacc[2][4];
    float m_i[2], l_p[2];
#pragma unroll
    for (int mt = 0; mt < 2; ++mt) {
#pragma unroll
      for (int d = 0; d < 4; ++d) oacc[mt][d] = (floatx4){0.f, 0.f, 0.f, 0.f};
      m_i[mt] = NEG_BIG; l_p[mt] = 0.f;
    }

    const int jtEnd = 2 * qt + 2;

    // stage tile 0 into buf 0
    {
      const bf16* kp = kbase + (size_t)srow * LDQ;
      *(int4*)&sK [0][srow][sseg]     = *(const int4*)kp;
      *(int4*)&sK [0][srow][sseg + 8] = *(const int4*)(kp + 8);
      *(int4*)&sVt[0][srow][sseg]     = *(const int4*)vbase;
      *(int4*)&sVt[0][srow][sseg + 8] = *(const int4*)(vbase + 8);
    }
    __syncthreads();

    int cur = 0;
    for (int jt = 0; jt < jtEnd; ++jt) {
      // ---- prefetch next tile into regs (global; latency hides under compute) ----
      int4 kr0, kr1, vr0, vr1;
      const bool pre = (jt + 1 < jtEnd);
      if (pre) {
        const bf16* kp2 = kbase + (size_t)((jt + 1) * 64 + srow) * LDQ;
        kr0 = *(const int4*)kp2;
        kr1 = *(const int4*)(kp2 + 8);
        const bf16* vp2 = vbase + (jt + 1) * 64;
        vr0 = *(const int4*)vp2;
        vr1 = *(const int4*)(vp2 + 8);
      }

      // ---- S^T = K Q^T: lane holds S[kv=nb*16+quad*4+i][q=l15] in sfr[mt][nb][i] ----
      floatx4 sfr[2][4];
#pragma unroll
      for (int mt = 0; mt < 2; ++mt)
#pragma unroll
        for (int nb = 0; nb < 4; ++nb) sfr[mt][nb] = (floatx4){0.f, 0.f, 0.f, 0.f};
#pragma unroll
      for (int kk = 0; kk < 2; ++kk) {
#pragma unroll
        for (int nb = 0; nb < 4; ++nb) {
          bf16x8 kf = __builtin_bit_cast(bf16x8,
              *(const shortx8*)&sK[cur][nb * 16 + l15][kk * 32 + quad * 8]);
          sfr[0][nb] = __builtin_amdgcn_mfma_f32_16x16x32_bf16(kf, qa[0][kk], sfr[0][nb], 0, 0, 0);
          sfr[1][nb] = __builtin_amdgcn_mfma_f32_16x16x32_bf16(kf, qa[1][kk], sfr[1][nb], 0, 0, 0);
        }
      }

      // ---- per mt: mask, in-lane row softmax with T13 defer ----
#pragma unroll
      for (int mt = 0; mt < 2; ++mt) {
        if (jt >= 2 * qt) {  // diagonal-crossing tiles only
          const int rg = q0 + w * 32 + mt * 16 + l15;
#pragma unroll
          for (int nb = 0; nb < 4; ++nb)
#pragma unroll
            for (int i = 0; i < 4; ++i) {
              int jg = jt * 64 + nb * 16 + quad * 4 + i;
              if (jg > rg) sfr[mt][nb][i] = NEG_BIG;
            }
        }
        // row max: 16 in-lane values + cross-quad reduce
        float m = fmaxf(fmaxf(sfr[mt][0][0], sfr[mt][0][1]), fmaxf(sfr[mt][0][2], sfr[mt][0][3]));
#pragma unroll
        for (int nb = 1; nb < 4; ++nb)
#pragma unroll
          for (int i = 0; i < 4; ++i) m = fmaxf(m, sfr[mt][nb][i]);
        m = fmaxf(m, __shfl_xor(m, 16));
        m = fmaxf(m, __shfl_xor(m, 32));

        bool grow = m > m_i[mt] + 8.f;
        if (__any((int)grow)) {
          float Mn = fmaxf(m_i[mt], m);
          float alpha = __expf(m_i[mt] - Mn);   // quad-uniform per l15-row
          m_i[mt] = Mn;
          l_p[mt] *= alpha;
#pragma unroll
          for (int i = 0; i < 4; ++i) {
            float ai = __shfl(alpha, (lane & 48) | (quad * 4 + i));
#pragma unroll
            for (int d = 0; d < 4; ++d) oacc[mt][d][i] *= ai;
          }
        }
        // exp in place + row-partial sum (lane-local)
        float rs = 0.f;
#pragma unroll
        for (int nb = 0; nb < 4; ++nb)
#pragma unroll
          for (int i = 0; i < 4; ++i) {
            float pv = __expf(sfr[mt][nb][i] - m_i[mt]);
            sfr[mt][nb][i] = pv;
            rs += pv;
          }
        l_p[mt] += rs;
      }

      // ---- O += P V: P as in-register A-frags (sigma-permuted), V via 2x ds_read_b64 --
#pragma unroll
      for (int kk = 0; kk < 2; ++kk) {
        bf16x8 pf0, pf1;
#pragma unroll
        for (int e = 0; e < 4; ++e) {
          pf0[e]     = (__bf16)sfr[0][2 * kk][e];
          pf0[e + 4] = (__bf16)sfr[0][2 * kk + 1][e];
          pf1[e]     = (__bf16)sfr[1][2 * kk][e];
          pf1[e + 4] = (__bf16)sfr[1][2 * kk + 1][e];
        }
#pragma unroll
        for (int db = 0; db < 4; ++db) {
          const short* vrow = &sVt[cur][db * 16 + l15][0];
          shortx4 va = *(const shortx4*)(vrow + kk * 32 + quad * 4);
          shortx4 vb = *(const shortx4*)(vrow + kk * 32 + 16 + quad * 4);
          bf16x8 vf = __builtin_bit_cast(bf16x8,
              __builtin_shufflevector(va, vb, 0, 1, 2, 3, 4, 5, 6, 7));
          oacc[0][db] = __builtin_amdgcn_mfma_f32_16x16x32_bf16(pf0, vf, oacc[0][db], 0, 0, 0);
          oacc[1][db] = __builtin_amdgcn_mfma_f32_16x16x32_bf16(pf1, vf, oacc[1][db], 0, 0, 0);
        }
      }

      // ---- write prefetched tile into the other buffer; single barrier ----
      if (pre) {
        *(int4*)&sK [cur ^ 1][srow][sseg]     = kr0;
        *(int4*)&sK [cur ^ 1][srow][sseg + 8] = kr1;
        *(int4*)&sVt[cur ^ 1][srow][sseg]     = vr0;
        *(int4*)&sVt[cur ^ 1][srow][sseg + 8] = vr1;
      }
      __syncthreads();
      cur ^= 1;
    }

    // ---- epilogue: cross-quad l reduce, alpha-style shfl for O-rows, store ----
#pragma unroll
    for (int mt = 0; mt < 2; ++mt) {
      float l = l_p[mt];
      l += __shfl_xor(l, 16);
      l += __shfl_xor(l, 32);
      float inv = 1.f / l;
#pragma unroll
      for (int i = 0; i < 4; ++i) {
        float ii = __shfl(inv, (lane & 48) | (quad * 4 + i));
        bf16* op = O + (size_t)(b * S + q0 + w * 32 + mt * 16 + quad * 4 + i) * D + h * 64 + l15;
#pragma unroll
        for (int db = 0; db < 4; ++db)
          op[db * 16] = __float2bfloat16(oacc[mt][db][i] * ii);
      }
    }
  }
}

// ---------------- launch ----------------
// ws layout (bf16 elements from ws16 = d_ws + 16; flag int at d_ws):
//   xb 8.4M | cosb/sinb 131k | bt_qkv 6.3M | wot 4.2M | qkv 12.6M  (~63.4 MB)
// Vt (2M elems = 4 MB) reuses bt_qkv, which is dead after the QKV GEMM.
extern "C" void kernel_launch(void* const* d_in, const int* in_sizes, int n_in,
                              void* d_out, int out_size, void* d_ws, size_t ws_size,
                              hipStream_t stream) {
  const void* x    = d_in[0];
  const void* cosp = d_in[1];
  const void* sinp = d_in[2];
  const void* wq   = d_in[3];
  const void* wk   = d_in[4];
  const void* wv   = d_in[5];
  const void* wo   = d_in[6];

  int* flag = (int*)d_ws;
  bf16* ws16 = (bf16*)((char*)d_ws + 16);
  bf16* xb     = ws16;
  bf16* cosb   = xb + (size_t)8388608;
  bf16* sinb   = cosb + 131072;
  bf16* bt_qkv = sinb + 131072;
  bf16* wot    = bt_qkv + (size_t)3072 * 2048;
  bf16* qkv    = wot + (size_t)2048 * 2048;
  bf16* o      = xb;      // x dead after QKV GEMM; attn output reuses it
  bf16* vt     = bt_qkv;  // weights dead after QKV GEMM; Vt reuses the slot

  sniff_k<<<1, 1, 0, stream>>>(cosp, flag);

  conv_k<<<(1048576 + 255) / 256, 256, 0, stream>>>(x, xb, 1048576, flag);
  conv_k<<<(16384 + 255) / 256, 256, 0, stream>>>(cosp, cosb, 16384, flag);
  conv_k<<<(16384 + 255) / 256, 256, 0, stream>>>(sinp, sinb, 16384, flag);

  dim3 tb(32, 8);
  transpose_conv_k<<<dim3(64, 64), tb, 0, stream>>>(wq, bt_qkv, 2048, flag);
  transpose_conv_k<<<dim3(16, 64), tb, 0, stream>>>(wk, bt_qkv + (size_t)2048 * 2048, 512, flag);
  transpose_conv_k<<<dim3(16, 64), tb, 0, stream>>>(wv, bt_qkv + (size_t)2560 * 2048, 512, flag);
  transpose_conv_k<<<dim3(64, 64), tb, 0, stream>>>(wo, wot, 2048, flag);

  // QKV projection: (4096,2048) @ (2048,3072), bf16 out — 256^2 tiles, 192 blocks
  gemm256<<<dim3(192), 512, 0, stream>>>(xb, bt_qkv, qkv, 4096, 3072, 2048, flag, 0);

  rope_k<<<2560, 256, 0, stream>>>(qkv, cosb, sinb);

  // V pre-transpose into the dead weight slot
  vt_k<<<dim3(32, 8, 2), 256, 0, stream>>>(qkv, vt);

  // attention: 512 uniform blocks (phase pair in-block), 8x32x2 grid
  attn_k<<<dim3(8, 32, 2), 256, 0, stream>>>(qkv, vt, o);

  // output projection: (4096,2048) @ (2048,2048) — 128 blocks; dtype follows input
  gemm256<<<dim3(128), 512, 0, stream>>>(o, wot, d_out, 4096, 2048, 2048, flag, 1);
}

// Round 7
// 333.878 us; speedup vs baseline: 1.3320x; 1.0473x over previous
//
#include <hip/hip_runtime.h>
#include <hip/hip_bf16.h>

using bf16 = __hip_bfloat16;

typedef float floatx4 __attribute__((ext_vector_type(4)));
typedef short shortx8 __attribute__((ext_vector_type(8)));
typedef short shortx4 __attribute__((ext_vector_type(4)));
typedef __bf16 bf16x8 __attribute__((ext_vector_type(8)));

#define NEG_BIG -3.0e38f

// async global->LDS DMA, 16 B per lane; LDS dest = wave-uniform base + lane*16
#define GLOAD_LDS16(g, l)                                                     \
  __builtin_amdgcn_global_load_lds(                                           \
      (const __attribute__((address_space(1))) unsigned int*)(g),             \
      (__attribute__((address_space(3))) unsigned int*)(l), 16, 0, 0)

__device__ __forceinline__ float bf2f(short s) {
  union { unsigned int u; float f; } x;
  x.u = ((unsigned int)(unsigned short)s) << 16;
  return x.f;
}

// ---------------- dtype sniff: cos[0]==1.0 exactly.
// fp32 -> word0 = 0x3F800000 ; bf16 -> word0 = 0x3F803F80 (two packed 1.0's)
__global__ void sniff_k(const void* __restrict__ cosp, int* __restrict__ flag) {
  unsigned w = *(const unsigned*)cosp;
  *flag = (w == 0x3F800000u) ? 1 : 0;  // 1 = inputs are fp32
}

// ---------------- generic input -> bf16 convert, vectorized x8 ----------------
__global__ void conv_k(const void* __restrict__ src, bf16* __restrict__ dst, int n8,
                       const int* __restrict__ flag) {
  int i = blockIdx.x * blockDim.x + threadIdx.x;
  if (i >= n8) return;
  shortx8 r;
  if (*flag) {
    const float4* s4 = (const float4*)src;
    float4 x0 = s4[i * 2], x1 = s4[i * 2 + 1];
    float xs[8] = {x0.x, x0.y, x0.z, x0.w, x1.x, x1.y, x1.z, x1.w};
#pragma unroll
    for (int e = 0; e < 8; ++e)
      r[e] = (short)__bfloat16_as_ushort(__float2bfloat16(xs[e]));
  } else {
    r = ((const shortx8*)src)[i];
  }
  *(shortx8*)(dst + (size_t)i * 8) = r;
}

// ---------------- fused convert + transpose: src (2048, C) -> dst (C, 2048) bf16 ------
__global__ void transpose_conv_k(const void* __restrict__ src, bf16* __restrict__ dst,
                                 int C, const int* __restrict__ flag) {
  __shared__ bf16 tile[32][33];
  int fp32 = *flag;
  int tx = threadIdx.x, ty = threadIdx.y;
  int c0 = blockIdx.x * 32, r0 = blockIdx.y * 32;
#pragma unroll
  for (int i = 0; i < 32; i += 8) {
    size_t idx = (size_t)(r0 + ty + i) * C + c0 + tx;
    tile[ty + i][tx] = fp32 ? __float2bfloat16(((const float*)src)[idx])
                            : ((const bf16*)src)[idx];
  }
  __syncthreads();
#pragma unroll
  for (int i = 0; i < 32; i += 8)
    dst[(size_t)(c0 + ty + i) * 2048 + r0 + tx] = tile[tx][ty + i];
}

// ---------------- GEMM BMx256: C(M,N) = A(M,K) @ Bt(N,K)^T, bf16 in, fp32 acc --------
// R6 post-mortem: the 256^2 ring kernel works, but out-proj's 128-block grid ran at
// 50% CU utilization (1 block/CU). Template on BM:
//   BM=256 (QKV, 192 blocks, 75% util): per-wave 128x64, acc[8][4], 4 loads/thread.
//   BM=128 (out-proj, 256 blocks, 100% util): per-wave 64x64, acc[4][4], 3 loads/thread.
// Shared structure: 8 waves (512 thr), 4-deep LDS ring of K=32 tiles, depth-2
// prefetch via global_load_lds, ONE raw s_barrier + counted vmcnt per K-tile (T4:
// never drain in-loop). Safety: stage(t+2) overwrites buf of t-2; issued after
// barrier(t-1) which is after all waves' compute(t-2). T2-lite swizzle: 64B rows have
// 4 16B slots; slot ^= (row&3) applied on the per-lane GLOBAL source (linear DMA
// dest, rule #21) and on ds_read addresses. T1 XCD swizzle (grids % 8 == 0).
template<int BM>
__global__ __launch_bounds__(512) void gemm256(const bf16* __restrict__ A,
                                               const bf16* __restrict__ Bt,
                                               void* __restrict__ Cp,
                                               int M, int N, int K,
                                               const int* __restrict__ flag,
                                               int f32out_en) {
  constexpr int NR = BM / 32;          // row frags per wave: 8 or 4
  constexpr int ABASE = BM * 32;       // A region shorts: 8192 or 4096
  constexpr int BUFS = ABASE + 8192;   // + B region (256x32 shorts)
  __shared__ __align__(16) short lds[4][BUFS];
  const int f32out = f32out_en ? *flag : 0;
  const int tid = threadIdx.x;
  const int w = tid >> 6, lane = tid & 63;
  const int wr = w >> 2, wc = w & 3;
  const int quad = lane >> 4, l15 = lane & 15;

  // XCD-aware bijective swizzle (nwg % 8 == 0 for all launches)
  const int nwg = gridDim.x;
  const int id = blockIdx.x;
  const int swz = (id & 7) * (nwg >> 3) + (id >> 3);
  const int nbx = N >> 8;
  const int bx = swz % nbx, by = swz / nbx;
  const int m0 = by * BM, n0 = bx << 8;

  // staging source (inverse-swizzled): lane covers row rl, 16B slot (lane&3)^(rl&3)
  const int rl = lane >> 2;
  const int c8 = (((lane & 3) ^ (rl & 3)) << 3);
  const bf16 *gA0, *gA1;
  if constexpr (BM == 256) {
    gA0 = A + (size_t)(m0 + w * 32 + rl) * K + c8;
    gA1 = gA0 + (size_t)16 * K;
  } else {
    gA0 = A + (size_t)(m0 + w * 16 + rl) * K + c8;
    gA1 = gA0;  // unused
  }
  const bf16* gB0 = Bt + (size_t)(n0 + w * 32 + rl) * K + c8;
  const bf16* gB1 = gB0 + (size_t)16 * K;

  floatx4 acc[NR][4];
#pragma unroll
  for (int r = 0; r < NR; ++r)
#pragma unroll
    for (int c = 0; c < 4; ++c)
      acc[r][c] = (floatx4){0.f, 0.f, 0.f, 0.f};

  // swizzled ds_read offsets (shorts); frag row & 3 == l15 & 3
  const int xr = (quad * 8) ^ ((l15 & 3) << 3);
  const int aoff = (wr * (BM / 2) + l15) * 32 + xr;
  const int boff = ABASE + (wc * 64 + l15) * 32 + xr;

  const int nkt = K >> 5;

  auto STAGE = [&](int tt) {
    short* d_ = &lds[tt & 3][0];
    const int k0_ = tt << 5;
    if constexpr (BM == 256) {
      GLOAD_LDS16(gA0 + k0_, d_ + (w << 10));
      GLOAD_LDS16(gA1 + k0_, d_ + (w << 10) + 512);
    } else {
      GLOAD_LDS16(gA0 + k0_, d_ + (w << 9));
    }
    GLOAD_LDS16(gB0 + k0_, d_ + ABASE + (w << 10));
    GLOAD_LDS16(gB1 + k0_, d_ + ABASE + (w << 10) + 512);
  };

  STAGE(0);
  STAGE(1);

  for (int t = 0; t < nkt; ++t) {
    if (t + 2 < nkt) {
      STAGE(t + 2);
      // tile t's own loads complete; 2 tiles (2L loads) stay in flight
      if constexpr (BM == 256) asm volatile("s_waitcnt vmcnt(8)" ::: "memory");
      else                     asm volatile("s_waitcnt vmcnt(6)" ::: "memory");
    } else if (t + 1 < nkt) {
      if constexpr (BM == 256) asm volatile("s_waitcnt vmcnt(4)" ::: "memory");
      else                     asm volatile("s_waitcnt vmcnt(3)" ::: "memory");
    } else {
      asm volatile("s_waitcnt vmcnt(0)" ::: "memory");
    }
    __builtin_amdgcn_s_barrier();
    __builtin_amdgcn_sched_barrier(0);  // keep ds_reads below the barrier

    const short* bufS = &lds[t & 3][0];
    bf16x8 af[NR], bfr[4];
#pragma unroll
    for (int r = 0; r < NR; ++r)
      af[r] = __builtin_bit_cast(bf16x8, *(const shortx8*)(bufS + aoff + r * 512));
#pragma unroll
    for (int c = 0; c < 4; ++c)
      bfr[c] = __builtin_bit_cast(bf16x8, *(const shortx8*)(bufS + boff + c * 512));
#pragma unroll
    for (int r = 0; r < NR; ++r)
#pragma unroll
      for (int c = 0; c < 4; ++c)
        acc[r][c] = __builtin_amdgcn_mfma_f32_16x16x32_bf16(af[r], bfr[c], acc[r][c], 0, 0, 0);
  }

#pragma unroll
  for (int r = 0; r < NR; ++r) {
#pragma unroll
    for (int c = 0; c < 4; ++c) {
      int mrow = m0 + wr * (BM / 2) + r * 16 + quad * 4;
      int ncol = n0 + wc * 64 + c * 16 + l15;
      if (f32out) {
#pragma unroll
        for (int i = 0; i < 4; ++i)
          ((float*)Cp)[(size_t)(mrow + i) * N + ncol] = acc[r][c][i];
      } else {
#pragma unroll
        for (int i = 0; i < 4; ++i)
          ((bf16*)Cp)[(size_t)(mrow + i) * N + ncol] = __float2bfloat16(acc[r][c][i]);
      }
    }
  }
}

// ---------------- RoPE in-place on q (heads 0..31) and k (kv heads 0..7) ----------------
__global__ void rope_k(bf16* __restrict__ qkv, const bf16* __restrict__ cosb,
                       const bf16* __restrict__ sinb) {
  int idx = blockIdx.x * blockDim.x + threadIdx.x;  // 4096*40*4 = 655360
  int i8 = (idx & 3) * 8;
  int head = (idx >> 2) % 40;
  int m = idx / 160;
  if (m >= 4096) return;
  int p = m & 2047;
  size_t base = (size_t)m * 3072 + (head < 32 ? head * 64 : 2048 + (head - 32) * 64);
  shortx8 a8 = *(const shortx8*)(qkv + base + i8);
  shortx8 b8 = *(const shortx8*)(qkv + base + 32 + i8);
  const bf16* cp = cosb + p * 64 + i8;
  const bf16* sp = sinb + p * 64 + i8;
  shortx8 c0 = *(const shortx8*)cp;
  shortx8 s0 = *(const shortx8*)sp;
  shortx8 c1 = *(const shortx8*)(cp + 32);
  shortx8 s1 = *(const shortx8*)(sp + 32);
  shortx8 ra, rb;
#pragma unroll
  for (int e = 0; e < 8; ++e) {
    float a = bf2f(a8[e]), bb = bf2f(b8[e]);
    ra[e] = (short)__bfloat16_as_ushort(__float2bfloat16(a * bf2f(c0[e]) - bb * bf2f(s0[e])));
    rb[e] = (short)__bfloat16_as_ushort(__float2bfloat16(bb * bf2f(c1[e]) + a * bf2f(s1[e])));
  }
  *(shortx8*)(qkv + base + i8) = ra;
  *(shortx8*)(qkv + base + 32 + i8) = rb;
}

// ---------------- V pre-transpose: qkv V region -> Vt[b][kvh][d][kv] (plain) ----------
__global__ void vt_k(const bf16* __restrict__ qkv, bf16* __restrict__ Vt) {
  __shared__ __align__(16) short tile[64][72];
  const int jt = blockIdx.x, kvh = blockIdx.y, b = blockIdx.z;
  const int t = threadIdx.x;
  const int r = t >> 2, seg = (t & 3) * 16;
  const bf16* src = qkv + (size_t)(b * 2048 + jt * 64 + r) * 3072 + 2560 + kvh * 64 + seg;
  *(int4*)&tile[r][seg]     = *(const int4*)src;
  *(int4*)&tile[r][seg + 8] = *(const int4*)(src + 8);
  __syncthreads();
  bf16* dst = Vt + ((size_t)(b * 8 + kvh) * 64 + r) * 2048 + jt * 64 + seg;
  short out[16];
#pragma unroll
  for (int e = 0; e < 16; ++e)
    out[e] = tile[seg + e][r];
  *(int4*)dst       = *(int4*)&out[0];
  *(int4*)(dst + 8) = *(int4*)&out[8];
}

// ---------------- flash attention (causal, GQA 4:1) — swapped-QK^T, in-reg softmax ---
// R5 structure (80.6 us). This round adds T5 s_setprio(1) around the two MFMA
// clusters: 2 blocks/CU at independent phases give the CU scheduler something to
// arbitrate (m191: +4-7% on attn; m190: null on lockstep GEMM, so GEMM untouched).
__global__ __launch_bounds__(256) void attn_k(const bf16* __restrict__ qkv,
                                              const bf16* __restrict__ Vt,
                                              bf16* __restrict__ O) {
  const int S = 2048, LDQ = 3072, D = 2048;
  const int p = blockIdx.x, h = blockIdx.y, b = blockIdx.z;
  const int kvh = h >> 2;
  const int tid = threadIdx.x;
  const int w = tid >> 6, lane = tid & 63;
  const int quad = lane >> 4, l15 = lane & 15;

  __shared__ __align__(16) short sK [2][64][72];  // [buf][kv pos][hd]
  __shared__ __align__(16) short sVt[2][64][72];  // [buf][hd][kv pos]

  const int srow = tid >> 2, sseg = (tid & 3) * 16;
  const bf16* kbase = qkv + (size_t)(b * S) * LDQ + 2048 + kvh * 64 + sseg;       // row=kv
  const bf16* vbase = Vt + ((size_t)(b * 8 + kvh) * 64 + srow) * 2048 + sseg;     // row=d

  for (int phase = 0; phase < 2; ++phase) {
    const int qt = phase ? (15 - p) : p;
    const int q0 = qt * 128;

    // Q fragments: 2 sub-tiles x 2 k-halves, pre-scaled by 1/sqrt(64) (exact in bf16)
    bf16x8 qa[2][2];
#pragma unroll
    for (int mt = 0; mt < 2; ++mt) {
      const bf16* qp = qkv + (size_t)(b * S + q0 + w * 32 + mt * 16 + l15) * LDQ + h * 64 + quad * 8;
      qa[mt][0] = __builtin_bit_cast(bf16x8, *(const shortx8*)qp);
      qa[mt][1] = __builtin_bit_cast(bf16x8, *(const shortx8*)(qp + 32));
    }
#pragma unroll
    for (int mt = 0; mt < 2; ++mt)
#pragma unroll
      for (int kk = 0; kk < 2; ++kk)
#pragma unroll
        for (int e = 0; e < 8; ++e)
          qa[mt][kk][e] = (__bf16)((float)qa[mt][kk][e] * 0.125f);

    floatx4 oacc[2][4];
    float m_i[2], l_p[2];
#pragma unroll
    for (int mt = 0; mt < 2; ++mt) {
#pragma unroll
      for (int d = 0; d < 4; ++d) oacc[mt][d] = (floatx4){0.f, 0.f, 0.f, 0.f};
      m_i[mt] = NEG_BIG; l_p[mt] = 0.f;
    }

    const int jtEnd = 2 * qt + 2;

    // stage tile 0 into buf 0
    {
      const bf16* kp = kbase + (size_t)srow * LDQ;
      *(int4*)&sK [0][srow][sseg]     = *(const int4*)kp;
      *(int4*)&sK [0][srow][sseg + 8] = *(const int4*)(kp + 8);
      *(int4*)&sVt[0][srow][sseg]     = *(const int4*)vbase;
      *(int4*)&sVt[0][srow][sseg + 8] = *(const int4*)(vbase + 8);
    }
    __syncthreads();

    int cur = 0;
    for (int jt = 0; jt < jtEnd; ++jt) {
      // ---- prefetch next tile into regs (global; latency hides under compute) ----
      int4 kr0, kr1, vr0, vr1;
      const bool pre = (jt + 1 < jtEnd);
      if (pre) {
        const bf16* kp2 = kbase + (size_t)((jt + 1) * 64 + srow) * LDQ;
        kr0 = *(const int4*)kp2;
        kr1 = *(const int4*)(kp2 + 8);
        const bf16* vp2 = vbase + (jt + 1) * 64;
        vr0 = *(const int4*)vp2;
        vr1 = *(const int4*)(vp2 + 8);
      }

      // ---- S^T = K Q^T: lane holds S[kv=nb*16+quad*4+i][q=l15] in sfr[mt][nb][i] ----
      floatx4 sfr[2][4];
#pragma unroll
      for (int mt = 0; mt < 2; ++mt)
#pragma unroll
        for (int nb = 0; nb < 4; ++nb) sfr[mt][nb] = (floatx4){0.f, 0.f, 0.f, 0.f};
      __builtin_amdgcn_s_setprio(1);
#pragma unroll
      for (int kk = 0; kk < 2; ++kk) {
#pragma unroll
        for (int nb = 0; nb < 4; ++nb) {
          bf16x8 kf = __builtin_bit_cast(bf16x8,
              *(const shortx8*)&sK[cur][nb * 16 + l15][kk * 32 + quad * 8]);
          sfr[0][nb] = __builtin_amdgcn_mfma_f32_16x16x32_bf16(kf, qa[0][kk], sfr[0][nb], 0, 0, 0);
          sfr[1][nb] = __builtin_amdgcn_mfma_f32_16x16x32_bf16(kf, qa[1][kk], sfr[1][nb], 0, 0, 0);
        }
      }
      __builtin_amdgcn_s_setprio(0);

      // ---- per mt: mask, in-lane row softmax with T13 defer ----
#pragma unroll
      for (int mt = 0; mt < 2; ++mt) {
        if (jt >= 2 * qt) {  // diagonal-crossing tiles only
          const int rg = q0 + w * 32 + mt * 16 + l15;
#pragma unroll
          for (int nb = 0; nb < 4; ++nb)
#pragma unroll
            for (int i = 0; i < 4; ++i) {
              int jg = jt * 64 + nb * 16 + quad * 4 + i;
              if (jg > rg) sfr[mt][nb][i] = NEG_BIG;
            }
        }
        // row max: 16 in-lane values + cross-quad reduce
        float m = fmaxf(fmaxf(sfr[mt][0][0], sfr[mt][0][1]), fmaxf(sfr[mt][0][2], sfr[mt][0][3]));
#pragma unroll
        for (int nb = 1; nb < 4; ++nb)
#pragma unroll
          for (int i = 0; i < 4; ++i) m = fmaxf(m, sfr[mt][nb][i]);
        m = fmaxf(m, __shfl_xor(m, 16));
        m = fmaxf(m, __shfl_xor(m, 32));

        bool grow = m > m_i[mt] + 8.f;
        if (__any((int)grow)) {
          float Mn = fmaxf(m_i[mt], m);
          float alpha = __expf(m_i[mt] - Mn);   // quad-uniform per l15-row
          m_i[mt] = Mn;
          l_p[mt] *= alpha;
#pragma unroll
          for (int i = 0; i < 4; ++i) {
            float ai = __shfl(alpha, (lane & 48) | (quad * 4 + i));
#pragma unroll
            for (int d = 0; d < 4; ++d) oacc[mt][d][i] *= ai;
          }
        }
        // exp in place + row-partial sum (lane-local)
        float rs = 0.f;
#pragma unroll
        for (int nb = 0; nb < 4; ++nb)
#pragma unroll
          for (int i = 0; i < 4; ++i) {
            float pv = __expf(sfr[mt][nb][i] - m_i[mt]);
            sfr[mt][nb][i] = pv;
            rs += pv;
          }
        l_p[mt] += rs;
      }

      // ---- O += P V: P as in-register A-frags (sigma-permuted), V via 2x ds_read_b64 --
      __builtin_amdgcn_s_setprio(1);
#pragma unroll
      for (int kk = 0; kk < 2; ++kk) {
        bf16x8 pf0, pf1;
#pragma unroll
        for (int e = 0; e < 4; ++e) {
          pf0[e]     = (__bf16)sfr[0][2 * kk][e];
          pf0[e + 4] = (__bf16)sfr[0][2 * kk + 1][e];
          pf1[e]     = (__bf16)sfr[1][2 * kk][e];
          pf1[e + 4] = (__bf16)sfr[1][2 * kk + 1][e];
        }
#pragma unroll
        for (int db = 0; db < 4; ++db) {
          const short* vrow = &sVt[cur][db * 16 + l15][0];
          shortx4 va = *(const shortx4*)(vrow + kk * 32 + quad * 4);
          shortx4 vb = *(const shortx4*)(vrow + kk * 32 + 16 + quad * 4);
          bf16x8 vf = __builtin_bit_cast(bf16x8,
              __builtin_shufflevector(va, vb, 0, 1, 2, 3, 4, 5, 6, 7));
          oacc[0][db] = __builtin_amdgcn_mfma_f32_16x16x32_bf16(pf0, vf, oacc[0][db], 0, 0, 0);
          oacc[1][db] = __builtin_amdgcn_mfma_f32_16x16x32_bf16(pf1, vf, oacc[1][db], 0, 0, 0);
        }
      }
      __builtin_amdgcn_s_setprio(0);

      // ---- write prefetched tile into the other buffer; single barrier ----
      if (pre) {
        *(int4*)&sK [cur ^ 1][srow][sseg]     = kr0;
        *(int4*)&sK [cur ^ 1][srow][sseg + 8] = kr1;
        *(int4*)&sVt[cur ^ 1][srow][sseg]     = vr0;
        *(int4*)&sVt[cur ^ 1][srow][sseg + 8] = vr1;
      }
      __syncthreads();
      cur ^= 1;
    }

    // ---- epilogue: cross-quad l reduce, alpha-style shfl for O-rows, store ----
#pragma unroll
    for (int mt = 0; mt < 2; ++mt) {
      float l = l_p[mt];
      l += __shfl_xor(l, 16);
      l += __shfl_xor(l, 32);
      float inv = 1.f / l;
#pragma unroll
      for (int i = 0; i < 4; ++i) {
        float ii = __shfl(inv, (lane & 48) | (quad * 4 + i));
        bf16* op = O + (size_t)(b * S + q0 + w * 32 + mt * 16 + quad * 4 + i) * D + h * 64 + l15;
#pragma unroll
        for (int db = 0; db < 4; ++db)
          op[db * 16] = __float2bfloat16(oacc[mt][db][i] * ii);
      }
    }
  }
}

// ---------------- launch ----------------
// ws layout (bf16 elements from ws16 = d_ws + 16; flag int at d_ws):
//   xb 8.4M | cosb/sinb 131k | bt_qkv 6.3M | wot 4.2M | qkv 12.6M  (~63.4 MB)
// Vt (2M elems = 4 MB) reuses bt_qkv, which is dead after the QKV GEMM.
extern "C" void kernel_launch(void* const* d_in, const int* in_sizes, int n_in,
                              void* d_out, int out_size, void* d_ws, size_t ws_size,
                              hipStream_t stream) {
  const void* x    = d_in[0];
  const void* cosp = d_in[1];
  const void* sinp = d_in[2];
  const void* wq   = d_in[3];
  const void* wk   = d_in[4];
  const void* wv   = d_in[5];
  const void* wo   = d_in[6];

  int* flag = (int*)d_ws;
  bf16* ws16 = (bf16*)((char*)d_ws + 16);
  bf16* xb     = ws16;
  bf16* cosb   = xb + (size_t)8388608;
  bf16* sinb   = cosb + 131072;
  bf16* bt_qkv = sinb + 131072;
  bf16* wot    = bt_qkv + (size_t)3072 * 2048;
  bf16* qkv    = wot + (size_t)2048 * 2048;
  bf16* o      = xb;      // x dead after QKV GEMM; attn output reuses it
  bf16* vt     = bt_qkv;  // weights dead after QKV GEMM; Vt reuses the slot

  sniff_k<<<1, 1, 0, stream>>>(cosp, flag);

  conv_k<<<(1048576 + 255) / 256, 256, 0, stream>>>(x, xb, 1048576, flag);
  conv_k<<<(16384 + 255) / 256, 256, 0, stream>>>(cosp, cosb, 16384, flag);
  conv_k<<<(16384 + 255) / 256, 256, 0, stream>>>(sinp, sinb, 16384, flag);

  dim3 tb(32, 8);
  transpose_conv_k<<<dim3(64, 64), tb, 0, stream>>>(wq, bt_qkv, 2048, flag);
  transpose_conv_k<<<dim3(16, 64), tb, 0, stream>>>(wk, bt_qkv + (size_t)2048 * 2048, 512, flag);
  transpose_conv_k<<<dim3(16, 64), tb, 0, stream>>>(wv, bt_qkv + (size_t)2560 * 2048, 512, flag);
  transpose_conv_k<<<dim3(64, 64), tb, 0, stream>>>(wo, wot, 2048, flag);

  // QKV projection: (4096,2048) @ (2048,3072) — BM=256, 192 blocks (75% util)
  gemm256<256><<<dim3(192), 512, 0, stream>>>(xb, bt_qkv, qkv, 4096, 3072, 2048, flag, 0);

  rope_k<<<2560, 256, 0, stream>>>(qkv, cosb, sinb);

  // V pre-transpose into the dead weight slot
  vt_k<<<dim3(32, 8, 2), 256, 0, stream>>>(qkv, vt);

  // attention: 512 uniform blocks (phase pair in-block), 8x32x2 grid
  attn_k<<<dim3(8, 32, 2), 256, 0, stream>>>(qkv, vt, o);

  // output projection: (4096,2048) @ (2048,2048) — BM=128, 256 blocks (100% util)
  gemm256<128><<<dim3(256), 512, 0, stream>>>(o, wot, d_out, 4096, 2048, 2048, flag, 1);
}